// Round 13
// baseline (15604.440 us; speedup 1.0000x reference)
//
#include <hip/hip_runtime.h>
#include <hip/hip_bf16.h>
#include <hip/hip_fp16.h>
#include <math.h>

typedef short short8 __attribute__((ext_vector_type(8)));
typedef short short4v __attribute__((ext_vector_type(4)));
typedef float f32x4 __attribute__((ext_vector_type(4)));
typedef unsigned long long u64;

#define DEVI __device__ __forceinline__

DEVI float bf2f(short s){ union{unsigned u; float f;} x; x.u = ((unsigned)(unsigned short)s) << 16; return x.f; }

// system-scope relaxed (sc0 sc1: bypass L1/L2 to coherent point) — NO fences
DEVI void st_u32v(unsigned* p, unsigned v){ __hip_atomic_store(p, v, __ATOMIC_RELAXED, __HIP_MEMORY_SCOPE_SYSTEM); }
DEVI unsigned ld_u32v(const unsigned* p){ return __hip_atomic_load(p, __ATOMIC_RELAXED, __HIP_MEMORY_SCOPE_SYSTEM); }
DEVI u64  ld_u64v(const u64* p){ return __hip_atomic_load(p, __ATOMIC_RELAXED, __HIP_MEMORY_SCOPE_SYSTEM); }
DEVI unsigned bfbits(float f){ __hip_bfloat16 h = __float2bfloat16(f); unsigned short b; __builtin_memcpy(&b,&h,2); return (unsigned)b; }
DEVI unsigned f16bits(float f){ __half h = __float2half(f); unsigned short b; __builtin_memcpy(&b,&h,2); return (unsigned)b; }
DEVI float f16val(unsigned short b){ __half h; __builtin_memcpy(&h,&b,2); return __half2float(h); }

// V=32000 H=1024 S=512 B=16 T=128, SOS=1
// ws layout (bytes)
constexpr size_t o_wout   = 0;                          // bf16 [32000*1024]
constexpr size_t o_encbf  = 0;                          // overlay (dead before wout used)
constexpr size_t o_kbf    = 16777216;                   // overlay
constexpr size_t o_wkbf   = 33554432;                   // overlay
constexpr size_t o_wvbf   = 35651584;                   // overlay
constexpr size_t o_wqtbf  = 37748736;                   // overlay
constexpr size_t o_vt     = 41943040;                   // overlay: bf16 VT [16][1024][512]
constexpr size_t o_kq     = 65536000;                   // bf16 [8192*1024]; psum overlays after decode
constexpr size_t o_psum   = o_kq;                       // f32 [2048*256] (kq dead by then)
constexpr size_t o_vbf    = o_kq    + 16777216;         // bf16 [8192*1024]
constexpr size_t o_wih2   = o_vbf   + 16777216;         // bf16 [4096*1024]
constexpr size_t o_whh    = o_wih2  + 8388608;          // bf16 [4096*1024]
constexpr size_t o_hall   = o_whh   + 8388608;          // bf16 [2048*1024]
constexpr size_t o_gconst = o_hall  + 4194304;          // f32 [4096]
constexpr size_t o_sb     = o_gconst+ 16384;            // f32 [8192]
constexpr size_t o_hv     = o_sb    + 32768;            // u32 [16*1024] h (bf16|tag<<16)
constexpr size_t o_pv     = o_hv    + 65536;            // u32 [4][64][260] pctx slabs (bf16|tag) + f16 pL

// ---------------- elementwise converts ----------------
__global__ void k_convert(const float* __restrict__ src, __hip_bfloat16* __restrict__ dst, int n){
  int i = (blockIdx.x*blockDim.x + threadIdx.x)*4;
  int stride = gridDim.x*blockDim.x*4;
  for (; i < n; i += stride){
    float4 v = *(const float4*)(src+i);
    __hip_bfloat16 o[4] = {__float2bfloat16(v.x),__float2bfloat16(v.y),__float2bfloat16(v.z),__float2bfloat16(v.w)};
    *(short4v*)(dst+i) = *(const short4v*)o;
  }
}

// Wq [1024][1024] f32 -> WqT bf16 (dst[h][d] = src[d][h])
__global__ void k_tcvt(const float* __restrict__ src, __hip_bfloat16* __restrict__ dst){
  __shared__ float tile[64][65];
  int i0 = blockIdx.y*64, j0 = blockIdx.x*64;
  int tr = threadIdx.x >> 6, tc = threadIdx.x & 63;
  for (int p=0;p<16;p++){ int r = p*4 + tr; tile[r][tc] = src[(size_t)(i0+r)*1024 + j0+tc]; }
  __syncthreads();
  for (int p=0;p<16;p++){ int r = p*4 + tr; dst[(size_t)(j0+r)*1024 + i0+tc] = __float2bfloat16(tile[tc][r]); }
}

// Wih2[r][c] = W_ih[r][1024+c], r<4096
__global__ void k_extract(const float* __restrict__ src, __hip_bfloat16* __restrict__ dst){
  int i = blockIdx.x*blockDim.x + threadIdx.x;
  int stride = gridDim.x*blockDim.x;
  for (; i < 4096*1024; i += stride){
    int r = i >> 10, c = i & 1023;
    dst[i] = __float2bfloat16(src[((size_t)r << 11) + 1024 + c]);
  }
}

// init hv = encoder_h tagged 0; zero pv tags. base=hv: hv[16384] + pv[66560] words
__global__ void k_init(const float* __restrict__ eh, unsigned* __restrict__ base){
  int i = blockIdx.x*blockDim.x + threadIdx.x;
  if (i < 16384) base[i] = bfbits(eh[i]);   // tag 0
  else if (i < 82944) base[i] = 0u;
}

// gate_const[n] = b_ih[n] + b_hh[n] + emb[SOS]·W_ih[n, 0:1024]
__global__ void k_gconst(const float* __restrict__ emb, const float* __restrict__ Wih,
                         const float* __restrict__ bih, const float* __restrict__ bhh,
                         float* __restrict__ gc){
  int w = threadIdx.x >> 6, lane = threadIdx.x & 63;
  int n = blockIdx.x*4 + w;
  const float* er = emb + 1024;  // SOS = 1
  const float* wr = Wih + (size_t)n*2048;
  float acc = 0.f;
  for (int q=0;q<16;q++){ int k = lane*16+q; acc += er[k]*wr[k]; }
  for (int off=32; off; off>>=1) acc += __shfl_xor(acc, off);
  if (lane==0) gc[n] = acc + bih[n] + bhh[n];
}

// sb[r] = (bq · K[r,:]) / 32
__global__ void k_sb(const __hip_bfloat16* __restrict__ Kb, const float* __restrict__ bq,
                     float* __restrict__ sb){
  int w = threadIdx.x >> 6, lane = threadIdx.x & 63;
  int r = blockIdx.x*4 + w;
  const __hip_bfloat16* kr = Kb + (size_t)r*1024;
  float acc = 0.f;
  for (int q=0;q<16;q++){ int k = lane*16+q; acc += __bfloat162float(kr[k])*bq[k]; }
  for (int off=32; off; off>>=1) acc += __shfl_xor(acc, off);
  if (lane==0) sb[r] = acc * 0.03125f;
}

// V [16*512][1024] -> VT [16][1024][512]
__global__ void k_vtrans(const __hip_bfloat16* __restrict__ V, __hip_bfloat16* __restrict__ VT){
  __shared__ short t[64][65];
  int b = blockIdx.z, s0 = blockIdx.y*64, h0 = blockIdx.x*64;
  int r = threadIdx.x >> 6, c = threadIdx.x & 63;
  const short* vp = (const short*)V + ((size_t)(b*512 + s0))*1024 + h0;
  #pragma unroll
  for (int p=0;p<16;p++) t[p*4+r][c] = vp[(size_t)(p*4+r)*1024 + c];
  __syncthreads();
  short* op = (short*)VT + ((size_t)(b*1024 + h0))*512 + s0;
  #pragma unroll
  for (int p=0;p<16;p++) op[(size_t)(p*4+r)*512 + c] = t[c][p*4+r];
}

// ---------------- GEMM: C = scale*(A @ B^T) + bias ----------------
// EPI 0: C bf16 [M,N]. EPI 2: C f32 at d_out with row permutation + exp-partials to psum.
template<int EPI>
__global__ __launch_bounds__(256) void k_gemm(const __hip_bfloat16* __restrict__ A,
    const __hip_bfloat16* __restrict__ Bm, const float* __restrict__ bias,
    void* __restrict__ Cp, float* __restrict__ psum, int M, int N, int K, float scale){
  __shared__ __hip_bfloat16 sA[128*40];
  __shared__ __hip_bfloat16 sB[128*40];
  __shared__ float sPart[(EPI==2)?128:1][33];
  int tid = threadIdx.x;
  int lane = tid & 63, w = tid >> 6;
  int wr = w >> 1, wc = w & 1;
  int m0 = blockIdx.y*128, n0 = blockIdx.x*128;
  int lrow = lane & 15, lk = lane >> 4;
  f32x4 acc[4][4] = {};
  for (int k0 = 0; k0 < K; k0 += 32){
    __syncthreads();
    #pragma unroll
    for (int l0 = 0; l0 < 1024; l0 += 256){
      int l = l0 + tid;
      int half = l >> 9;
      int ch = l & 511;
      int row = ch >> 2, seg = ch & 3;
      const __hip_bfloat16* src = half ? (Bm + (size_t)(n0+row)*K + k0 + seg*8)
                                       : (A  + (size_t)(m0+row)*K + k0 + seg*8);
      __hip_bfloat16* dst = (half ? sB : sA) + row*40 + seg*8;
      *(short8*)dst = *(const short8*)src;
    }
    __syncthreads();
    short8 af[4], bfq[4];
    #pragma unroll
    for (int mi=0;mi<4;mi++) af[mi]  = *(short8*)(sA + (wr*64+mi*16+lrow)*40 + lk*8);
    #pragma unroll
    for (int ni=0;ni<4;ni++) bfq[ni] = *(short8*)(sB + (wc*64+ni*16+lrow)*40 + lk*8);
    #pragma unroll
    for (int mi=0;mi<4;mi++)
      #pragma unroll
      for (int ni=0;ni<4;ni++)
        acc[mi][ni] = __builtin_amdgcn_mfma_f32_16x16x32_bf16(af[mi], bfq[ni], acc[mi][ni], 0,0,0);
  }
  int crow0 = (lane>>4)*4;
  int ccol = lane & 15;
  float es[4][4];
  #pragma unroll
  for (int mi=0;mi<4;mi++)
    #pragma unroll
    for (int j=0;j<4;j++) es[mi][j] = 0.f;
  #pragma unroll
  for (int mi=0;mi<4;mi++)
    #pragma unroll
    for (int ni=0;ni<4;ni++){
      int gn = n0 + wc*64 + ni*16 + ccol;
      float bv = bias ? bias[gn] : 0.0f;
      #pragma unroll
      for (int j=0;j<4;j++){
        int gm = m0 + wr*64 + mi*16 + crow0 + j;
        float v = acc[mi][ni][j]*scale + bv;
        if (EPI==0){
          ((__hip_bfloat16*)Cp)[(size_t)gm*N + gn] = __float2bfloat16(v);
        } else {
          int tt = gm >> 4, bb = gm & 15;
          ((float*)Cp)[(size_t)(bb*128+tt)*N + gn] = v;
          es[mi][j] += __expf(v);
        }
      }
    }
  if (EPI==2){
    #pragma unroll
    for (int mi=0;mi<4;mi++)
      #pragma unroll
      for (int j=0;j<4;j++)
        sPart[wr*64+mi*16+crow0+j][wc*16+ccol] = es[mi][j];
    __syncthreads();
    int row = tid >> 1, hh = tid & 1;
    float s2 = 0.f;
    #pragma unroll
    for (int k=0;k<16;k++) s2 += sPart[row][hh*16+k];
    s2 += __shfl_xor(s2, 1);
    if (hh == 0){
      int gm = m0 + row;
      psum[(size_t)((gm&15)*128 + (gm>>4))*256 + blockIdx.x] = s2;
    }
  }
}

// ---------------- persistent decoder: 2-hop pos×dim-chunked partial-ctx dataflow ----------------
// 4 groups of 64 blocks (xcd=blk&7, slot=blk>>3, grp=xcd>>1, half=xcd&1); group owns
// batches 4g..4g+3. Every block has BOTH roles:
//  att: batch bloc=half*2+(slot>>4), unit u=slot&15 -> pos-chunk c=u>>2 (128 pos),
//       dim-slice d=u&3 (256 dims). Computes chunk scores (redundant x4 over d),
//       softmax exp + partial L, UNNORMALIZED pctx over its 256 dims from VT
//       (contiguous). Publishes slab of 256 bf16|tag words + f16 pL.
//  gate: j0=(half*32+slot)*16, weights register-resident; sums 4 chunk-partials per
//       dim, normalizes by sum-L, MFMA gates, LSTM, stores h. 2 hops/step.
// Safety: ALL h staged before pctx publish -> h@st+1 needs all pctx@st+1 needs all
// blocks done reading h@st. Tags exact-match, monotone.
__global__ __launch_bounds__(256, 1) void k_decode(
    const __hip_bfloat16* __restrict__ KQ, const __hip_bfloat16* __restrict__ VT,
    const float* __restrict__ sb, const __hip_bfloat16* __restrict__ Whh,
    const __hip_bfloat16* __restrict__ Wih2, const float* __restrict__ gconst,
    const float* __restrict__ ec,
    unsigned* __restrict__ hv, unsigned* __restrict__ pv,
    __hip_bfloat16* __restrict__ hall,
    float* __restrict__ outH, float* __restrict__ outC)
{
  __shared__ __attribute__((aligned(16))) __hip_bfloat16 h4L[4][1032];
  __shared__ __attribute__((aligned(16))) float eL[128];
  __shared__ float sSc[128];
  __shared__ __attribute__((aligned(16))) float sPf[1024];
  __shared__ float sSb[128];
  __shared__ float sGc[64];
  __shared__ float sRed[2];
  __shared__ float sLp[16];   // [r*4+c] partial L

  const int tid = threadIdx.x;
  const int lane = tid & 63, wv = tid >> 6;
  const int l16 = lane & 15, lhi = lane >> 4;
  const int blk = blockIdx.x;
  const int xcd = blk & 7, slot = blk >> 3;
  const int grp = xcd >> 1, half = xcd & 1;
  const int bloc = half*2 + (slot >> 4);
  const int u = slot & 15;
  const int pc = u >> 2;          // position chunk (128 positions)
  const int dd = u & 3;           // dim slice (256 dims)
  const int g4 = grp*4;
  const int b = g4 + bloc;
  const int j0 = (half*32 + slot) * 16;

  // gate-weight fragments: waves 0-1 Whh (h part), waves 2-3 Wih2 (ctx part)
  short8 wfrag[64];
  {
    const __hip_bfloat16* wsrc = (wv < 2) ? Whh : Wih2;
    const int koff = (wv & 1) * 512;
    #pragma unroll
    for (int tt = 0; tt < 4; tt++)
      #pragma unroll
      for (int kt = 0; kt < 16; kt++)
        wfrag[tt*16+kt] = *(const short8*)(wsrc + (size_t)(tt*1024 + j0 + l16)*1024 + koff + kt*32 + lhi*8);
  }
  if (tid < 128) sSb[tid] = sb[b*512 + pc*128 + tid];
  if (tid < 64) sGc[(tid>>4)*16 + (tid&15)] = gconst[(tid>>4)*1024 + j0 + (tid&15)];
  float creg = 0.f;
  if (tid < 64) creg = ec[(size_t)(g4 + (tid>>4))*1024 + j0 + (tid&15)];

  const __hip_bfloat16* kqBlk = KQ + ((size_t)(b*512 + pc*128))*1024;
  const int ar = (l16 < 4) ? l16 : 3;
  const short8 zfrag = {};
  f32x4 gacc[4] = {};

  unsigned* mySlab = pv + (size_t)(grp*64 + bloc*16 + pc*4 + dd)*260;

  // sentinels
  const unsigned* snH = hv + (size_t)g4*1024 + lane*16;              // h: any 64 words across group
  const unsigned* snP = pv + (size_t)(grp*64 + lane)*260;            // pctx: slab word 0 per producer

  for (int st = 0; st < 128; ++st){
    const unsigned wantH = (unsigned)st;
    const unsigned wantN = (unsigned)(st+1);

    // ---- hop 1: spin h sentinels, stage ALL 4 batches (before any publish!) ----
    { unsigned v; do { v = ld_u32v(snH); } while (!__all((int)((v>>16) == wantH))); }
    #pragma unroll
    for (int r = 0; r < 4; r++){
      const u64* s0 = (const u64*)(hv + (size_t)(g4 + r)*1024) + tid*2;
      u64 a0, a1; bool ok;
      do {
        a0 = ld_u64v(s0); a1 = ld_u64v(s0+1);
        ok = (((unsigned)a0>>16)==wantH) && ((unsigned)(a0>>48)==wantH)
          && (((unsigned)a1>>16)==wantH) && ((unsigned)(a1>>48)==wantH);
      } while(!ok);
      short4v o = { (short)(unsigned)a0, (short)(a0>>32), (short)(unsigned)a1, (short)(a1>>32) };
      *(short4v*)&h4L[r][tid*4] = o;
    }
    __syncthreads();

    // ---- att: scores for own 128-position chunk (redundant x4 over dim-slices) ----
    {
      int row = tid >> 1, kh = (tid & 1)*512;
      const __hip_bfloat16* kp = kqBlk + (size_t)row*1024 + kh;
      const __hip_bfloat16* hp = &h4L[bloc][kh];
      float acc = 0.f;
      #pragma unroll
      for (int q = 0; q < 64; q++){
        short8 kv = *(const short8*)(kp + q*8);
        short8 hv8 = *(const short8*)(hp + q*8);
        #pragma unroll
        for (int e2 = 0; e2 < 8; e2++) acc += bf2f(hv8[e2]) * bf2f(kv[e2]);
      }
      acc += __shfl_xor(acc, 1);
      if ((tid & 1) == 0) sSc[row] = acc + sSb[row];
    }
    __syncthreads();
    {
      float lp = 0.f;
      if (tid < 128){ float e = expf(sSc[tid]); eL[tid] = e; lp = e; }
      for (int off=32; off; off>>=1) lp += __shfl_xor(lp, off);
      if (lane == 0 && wv < 2) sRed[wv] = lp;
    }
    __syncthreads();
    // ---- pctx over own 256 dims (VT contiguous), publish slab ----
    {
      float Lp = sRed[0] + sRed[1];
      const __hip_bfloat16* vp = VT + ((size_t)(b*1024 + dd*256 + tid))*512 + pc*128;
      float acc = 0.f;
      #pragma unroll
      for (int q = 0; q < 16; q++){
        short8 vv = *(const short8*)(vp + q*8);
        #pragma unroll
        for (int e2 = 0; e2 < 8; e2++) acc += eL[q*8+e2]*bf2f(vv[e2]);
      }
      st_u32v(&mySlab[tid], bfbits(acc) | (wantN<<16));
      if (tid == 0) st_u32v(&mySlab[256], f16bits(Lp) | (wantN<<16));
    }
    // ---- h-part gate MFMA (waves 0-1) — overlaps pctx flight ----
    if (wv < 2){
      const int ko = (wv & 1) * 512;
      #pragma unroll
      for (int kt = 0; kt < 16; kt++){
        short8 a = *(const short8*)&h4L[ar][ko + kt*32 + lhi*8];
        a = (l16 < 4) ? a : zfrag;
        #pragma unroll
        for (int tt = 0; tt < 4; tt++)
          gacc[tt] = __builtin_amdgcn_mfma_f32_16x16x32_bf16(a, wfrag[tt*16+kt], gacc[tt], 0,0,0);
      }
    }
    __syncthreads();   // h4L reads complete before ctx overwrite

    // ---- hop 2: spin pctx sentinels; stage ctx = (sum chunks)/L -> h4L ----
    { unsigned v; do { v = ld_u32v(snP); } while (!__all((int)((v>>16) == wantN))); }
    {
      if (tid < 16){
        int r = tid >> 2, c2 = tid & 3;
        const unsigned* plw = pv + (size_t)(grp*64 + r*16 + c2*4)*260 + 256;
        unsigned lw;
        do { lw = ld_u32v(plw); } while ((lw>>16) != wantN);
        sLp[tid] = f16val((unsigned short)lw);
      }
      int r = tid >> 6, q = tid & 63;
      int d2 = q >> 4, off = (q & 15)*16;
      float acc[16];
      #pragma unroll
      for (int k = 0; k < 16; k++) acc[k] = 0.f;
      #pragma unroll
      for (int c2 = 0; c2 < 4; c2++){
        const u64* s = (const u64*)(pv + (size_t)(grp*64 + r*16 + c2*4 + d2)*260 + off);
        u64 v[8]; bool ok;
        do {
          ok = true;
          #pragma unroll
          for (int i=0;i<8;i++) v[i] = ld_u64v(s+i);
          #pragma unroll
          for (int i=0;i<8;i++) ok &= (((unsigned)v[i]>>16)==wantN) && ((unsigned)(v[i]>>48)==wantN);
        } while(!ok);
        #pragma unroll
        for (int i=0;i<8;i++){
          acc[2*i]   += bf2f((short)(unsigned)v[i]);
          acc[2*i+1] += bf2f((short)(v[i]>>32));
        }
      }
      __syncthreads();
      float Linv = 1.0f/(sLp[r*4]+sLp[r*4+1]+sLp[r*4+2]+sLp[r*4+3]);
      __hip_bfloat16 ob[16];
      #pragma unroll
      for (int k = 0; k < 16; k++) ob[k] = __float2bfloat16(acc[k]*Linv);
      *(short8*)&h4L[r][q*16]     = *(const short8*)&ob[0];
      *(short8*)&h4L[r][q*16 + 8] = *(const short8*)&ob[8];
    }
    __syncthreads();
    // ---- ctx-part gate MFMA (waves 2-3) ----
    if (wv >= 2){
      const int ko = (wv & 1) * 512;
      #pragma unroll
      for (int kt = 0; kt < 16; kt++){
        short8 a = *(const short8*)&h4L[ar][ko + kt*32 + lhi*8];
        a = (l16 < 4) ? a : zfrag;
        #pragma unroll
        for (int tt = 0; tt < 4; tt++)
          gacc[tt] = __builtin_amdgcn_mfma_f32_16x16x32_bf16(a, wfrag[tt*16+kt], gacc[tt], 0,0,0);
      }
    }
    if (lhi == 0){
      #pragma unroll
      for (int tt = 0; tt < 4; tt++)
        *(f32x4*)&sPf[(wv*64 + tt*16 + l16)*4] = gacc[tt];
    }
    #pragma unroll
    for (int tt = 0; tt < 4; tt++) gacc[tt] = (f32x4){0.f,0.f,0.f,0.f};
    __syncthreads();
    // ---- gates + LSTM + h store ----
    if (tid < 64){
      int bb = tid >> 4, jj = tid & 15;
      float gv[4];
      #pragma unroll
      for (int tt = 0; tt < 4; tt++){
        float s = sGc[tt*16 + jj];
        #pragma unroll
        for (int w2 = 0; w2 < 4; w2++) s += sPf[(w2*64 + tt*16 + jj)*4 + bb];
        gv[tt] = s;
      }
      float si = 1.f/(1.f+expf(-gv[0]));
      float sf = 1.f/(1.f+expf(-gv[1]));
      float so = 1.f/(1.f+expf(-gv[3]));
      float c2 = sf*creg + si*tanhf(gv[2]);
      float h2 = so*tanhf(c2);
      creg = c2;
      int gb = g4 + bb;
      unsigned hb = bfbits(h2);
      st_u32v(&hv[(size_t)gb*1024 + j0 + jj], hb | (wantN<<16));
      __hip_bfloat16 hbv; unsigned short hu = (unsigned short)hb; __builtin_memcpy(&hbv, &hu, 2);
      hall[((size_t)(st*16 + gb))*1024 + j0 + jj] = hbv;
      if (st == 127){ outH[gb*1024 + j0 + jj] = h2; outC[gb*1024 + j0 + jj] = c2; }
    }
    __syncthreads();   // h4L (ctx) consumption done before next-step h staging
  }
}

// ---------------- apply log-softmax using fused exp-partials ----------------
__global__ __launch_bounds__(256) void k_apply(float* __restrict__ out, const float* __restrict__ psum){
  int r = blockIdx.x;
  int tid = threadIdx.x;
  __shared__ float red[4];
  float s = (tid < 250) ? psum[(size_t)r*256 + tid] : 0.f;
  for (int off=32; off; off>>=1) s += __shfl_xor(s, off);
  if ((tid&63)==0) red[tid>>6] = s;
  __syncthreads();
  float L = logf(red[0]+red[1]+red[2]+red[3]);
  float* p = out + (size_t)r*32000;
  for (int i = tid*4; i < 32000; i += 1024){
    float4 v = *(float4*)(p+i);
    v.x-=L; v.y-=L; v.z-=L; v.w-=L;
    *(float4*)(p+i) = v;
  }
}

extern "C" void kernel_launch(void* const* d_in, const int* in_sizes, int n_in,
                              void* d_out, int out_size, void* d_ws, size_t ws_size,
                              hipStream_t stream){
  const float* enc = (const float*)d_in[0];
  const float* eh  = (const float*)d_in[1];
  const float* ec  = (const float*)d_in[2];
  const float* emb = (const float*)d_in[3];
  const float* Wq  = (const float*)d_in[4];
  const float* bq  = (const float*)d_in[5];
  const float* Wk  = (const float*)d_in[6];
  const float* bk  = (const float*)d_in[7];
  const float* Wv  = (const float*)d_in[8];
  const float* bv  = (const float*)d_in[9];
  const float* Wih = (const float*)d_in[10];
  const float* bih = (const float*)d_in[11];
  const float* Whh = (const float*)d_in[12];
  const float* bhh = (const float*)d_in[13];
  const float* Wo  = (const float*)d_in[14];
  const float* bo  = (const float*)d_in[15];

  char* ws = (char*)d_ws;
  __hip_bfloat16* encbf = (__hip_bfloat16*)(ws + o_encbf);
  __hip_bfloat16* kbf   = (__hip_bfloat16*)(ws + o_kbf);
  __hip_bfloat16* wkbf  = (__hip_bfloat16*)(ws + o_wkbf);
  __hip_bfloat16* wvbf  = (__hip_bfloat16*)(ws + o_wvbf);
  __hip_bfloat16* wqtbf = (__hip_bfloat16*)(ws + o_wqtbf);
  __hip_bfloat16* vt    = (__hip_bfloat16*)(ws + o_vt);
  __hip_bfloat16* woutbf= (__hip_bfloat16*)(ws + o_wout);
  __hip_bfloat16* kq    = (__hip_bfloat16*)(ws + o_kq);
  __hip_bfloat16* vbf   = (__hip_bfloat16*)(ws + o_vbf);
  __hip_bfloat16* wih2  = (__hip_bfloat16*)(ws + o_wih2);
  __hip_bfloat16* whhbf = (__hip_bfloat16*)(ws + o_whh);
  __hip_bfloat16* hall  = (__hip_bfloat16*)(ws + o_hall);
  float* gconst = (float*)(ws + o_gconst);
  float* sbp    = (float*)(ws + o_sb);
  unsigned* hvp = (unsigned*)(ws + o_hv);
  unsigned* pvp = (unsigned*)(ws + o_pv);
  float* psum   = (float*)(ws + o_psum);
  float* outP   = (float*)d_out;
  float* outH   = outP + 65536000;
  float* outC   = outH + 16384;

  // ---- precompute ----
  k_convert<<<1024,256,0,stream>>>(enc, encbf, 8388608);
  k_convert<<<256,256,0,stream>>>(Wk, wkbf, 1048576);
  k_convert<<<256,256,0,stream>>>(Wv, wvbf, 1048576);
  k_tcvt<<<dim3(16,16),256,0,stream>>>(Wq, wqtbf);
  k_gemm<0><<<dim3(8,64),256,0,stream>>>(encbf, wkbf, bk, kbf, nullptr, 8192,1024,1024, 1.f);
  k_gemm<0><<<dim3(8,64),256,0,stream>>>(encbf, wvbf, bv, vbf, nullptr, 8192,1024,1024, 1.f);
  k_gemm<0><<<dim3(8,64),256,0,stream>>>(kbf, wqtbf, (const float*)nullptr, kq, nullptr, 8192,1024,1024, 0.03125f);
  k_vtrans<<<dim3(16,8,16),256,0,stream>>>(vbf, vt);
  k_sb<<<2048,256,0,stream>>>(kbf, bq, sbp);
  k_extract<<<1024,256,0,stream>>>(Wih, wih2);
  k_convert<<<1024,256,0,stream>>>(Whh, whhbf, 4194304);
  k_gconst<<<1024,256,0,stream>>>(emb, Wih, bih, bhh, gconst);
  k_init<<<324,256,0,stream>>>(eh, hvp);

  // ---- recurrence: persistent 2-hop dataflow kernel ----
  {
    const __hip_bfloat16* a_kq = kq; const __hip_bfloat16* a_vt = vt;
    const float* a_sb = sbp; const __hip_bfloat16* a_whh = whhbf;
    const __hip_bfloat16* a_wih = wih2; const float* a_gc = gconst;
    const float* a_ec = ec;
    unsigned* a_h = hvp; unsigned* a_p = pvp;
    __hip_bfloat16* a_ha = hall;
    float* a_oh = outH; float* a_oc = outC;
    void* args[] = { &a_kq, &a_vt, &a_sb, &a_whh, &a_wih, &a_gc, &a_ec,
                     &a_h, &a_p, &a_ha, &a_oh, &a_oc };
    hipError_t err = hipLaunchCooperativeKernel((void*)k_decode, dim3(256), dim3(256),
                                                args, 0u, stream);
    if (err != hipSuccess){
      k_decode<<<256,256,0,stream>>>(kq, vt, sbp, whhbf, wih2, gconst, ec,
                                     hvp, pvp, hall, outH, outC);
    }
  }

  // ---- logits + fused log-softmax ----
  k_convert<<<2048,256,0,stream>>>(Wo, woutbf, 32768000);
  k_gemm<2><<<dim3(250,16),256,0,stream>>>(hall, woutbf, bo, d_out, psum, 2048,32000,1024, 1.f);
  k_apply<<<2048,256,0,stream>>>(outP, psum);
}

// Round 14
// 2630.290 us; speedup vs baseline: 5.9326x; 5.9326x over previous
//
#include <hip/hip_runtime.h>
#include <hip/hip_bf16.h>
#include <math.h>

typedef short short8 __attribute__((ext_vector_type(8)));
typedef short short4v __attribute__((ext_vector_type(4)));
typedef float f32x4 __attribute__((ext_vector_type(4)));
typedef unsigned long long u64;

#define DEVI __device__ __forceinline__

DEVI float bf2f(short s){ union{unsigned u; float f;} x; x.u = ((unsigned)(unsigned short)s) << 16; return x.f; }

// system-scope relaxed (sc0 sc1: bypass L1/L2 to coherent point) — NO fences anywhere
DEVI void st_u32v(unsigned* p, unsigned v){ __hip_atomic_store(p, v, __ATOMIC_RELAXED, __HIP_MEMORY_SCOPE_SYSTEM); }
DEVI unsigned ld_u32v(const unsigned* p){ return __hip_atomic_load(p, __ATOMIC_RELAXED, __HIP_MEMORY_SCOPE_SYSTEM); }
DEVI u64  ld_u64v(const u64* p){ return __hip_atomic_load(p, __ATOMIC_RELAXED, __HIP_MEMORY_SCOPE_SYSTEM); }
DEVI unsigned bfbits(float f){ __hip_bfloat16 h = __float2bfloat16(f); unsigned short b; __builtin_memcpy(&b,&h,2); return (unsigned)b; }

// V=32000 H=1024 S=512 B=16 T=128, SOS=1
// ws layout (bytes)
constexpr size_t o_wout   = 0;                          // bf16 [32000*1024]
constexpr size_t o_encbf  = 0;                          // overlay (dead before wout used)
constexpr size_t o_kbf    = 16777216;                   // overlay
constexpr size_t o_wkbf   = 33554432;                   // overlay
constexpr size_t o_wvbf   = 35651584;                   // overlay
constexpr size_t o_wqtbf  = 37748736;                   // overlay
constexpr size_t o_vt     = 41943040;                   // overlay: bf16 VT [16][1024][512]
constexpr size_t o_kq     = 65536000;                   // bf16 [8192*1024]; psum overlays after decode
constexpr size_t o_psum   = o_kq;                       // f32 [2048*256] (kq dead by then)
constexpr size_t o_vbf    = o_kq    + 16777216;         // bf16 [8192*1024]
constexpr size_t o_wih2   = o_vbf   + 16777216;         // bf16 [4096*1024]
constexpr size_t o_whh    = o_wih2  + 8388608;          // bf16 [4096*1024]
constexpr size_t o_hall   = o_whh   + 8388608;          // bf16 [2048*1024]
constexpr size_t o_gconst = o_hall  + 4194304;          // f32 [4096]
constexpr size_t o_sb     = o_gconst+ 16384;            // f32 [8192]
constexpr size_t o_hv     = o_sb    + 32768;            // u32 [16*1024] h (bf16|tag<<16)
constexpr size_t o_ev     = o_hv    + 65536;            // u32 [16*512]  e
constexpr size_t o_cv     = o_ev    + 32768;            // u32 [16*1024] ctx

// ---------------- elementwise converts ----------------
__global__ void k_convert(const float* __restrict__ src, __hip_bfloat16* __restrict__ dst, int n){
  int i = (blockIdx.x*blockDim.x + threadIdx.x)*4;
  int stride = gridDim.x*blockDim.x*4;
  for (; i < n; i += stride){
    float4 v = *(const float4*)(src+i);
    __hip_bfloat16 o[4] = {__float2bfloat16(v.x),__float2bfloat16(v.y),__float2bfloat16(v.z),__float2bfloat16(v.w)};
    *(short4v*)(dst+i) = *(const short4v*)o;
  }
}

// Wq [1024][1024] f32 -> WqT bf16 (dst[h][d] = src[d][h])
__global__ void k_tcvt(const float* __restrict__ src, __hip_bfloat16* __restrict__ dst){
  __shared__ float tile[64][65];
  int i0 = blockIdx.y*64, j0 = blockIdx.x*64;
  int tr = threadIdx.x >> 6, tc = threadIdx.x & 63;
  for (int p=0;p<16;p++){ int r = p*4 + tr; tile[r][tc] = src[(size_t)(i0+r)*1024 + j0+tc]; }
  __syncthreads();
  for (int p=0;p<16;p++){ int r = p*4 + tr; dst[(size_t)(j0+r)*1024 + i0+tc] = __float2bfloat16(tile[tc][r]); }
}

// Wih2[r][c] = W_ih[r][1024+c], r<4096
__global__ void k_extract(const float* __restrict__ src, __hip_bfloat16* __restrict__ dst){
  int i = blockIdx.x*blockDim.x + threadIdx.x;
  int stride = gridDim.x*blockDim.x;
  for (; i < 4096*1024; i += stride){
    int r = i >> 10, c = i & 1023;
    dst[i] = __float2bfloat16(src[((size_t)r << 11) + 1024 + c]);
  }
}

// init hv = encoder_h tagged 0; zero ev+cv. base = hv; hv[16384] ev[8192] cv[16384] contiguous.
__global__ void k_init(const float* __restrict__ eh, unsigned* __restrict__ base){
  int i = blockIdx.x*blockDim.x + threadIdx.x;
  if (i < 16384) base[i] = bfbits(eh[i]);   // tag 0
  else if (i < 40960) base[i] = 0u;
}

// gate_const[n] = b_ih[n] + b_hh[n] + emb[SOS]·W_ih[n, 0:1024]
__global__ void k_gconst(const float* __restrict__ emb, const float* __restrict__ Wih,
                         const float* __restrict__ bih, const float* __restrict__ bhh,
                         float* __restrict__ gc){
  int w = threadIdx.x >> 6, lane = threadIdx.x & 63;
  int n = blockIdx.x*4 + w;
  const float* er = emb + 1024;  // SOS = 1
  const float* wr = Wih + (size_t)n*2048;
  float acc = 0.f;
  for (int q=0;q<16;q++){ int k = lane*16+q; acc += er[k]*wr[k]; }
  for (int off=32; off; off>>=1) acc += __shfl_xor(acc, off);
  if (lane==0) gc[n] = acc + bih[n] + bhh[n];
}

// sb[r] = (bq · K[r,:]) / 32
__global__ void k_sb(const __hip_bfloat16* __restrict__ Kb, const float* __restrict__ bq,
                     float* __restrict__ sb){
  int w = threadIdx.x >> 6, lane = threadIdx.x & 63;
  int r = blockIdx.x*4 + w;
  const __hip_bfloat16* kr = Kb + (size_t)r*1024;
  float acc = 0.f;
  for (int q=0;q<16;q++){ int k = lane*16+q; acc += __bfloat162float(kr[k])*bq[k]; }
  for (int off=32; off; off>>=1) acc += __shfl_xor(acc, off);
  if (lane==0) sb[r] = acc * 0.03125f;
}

// V [16*512][1024] -> VT [16][1024][512]
__global__ void k_vtrans(const __hip_bfloat16* __restrict__ V, __hip_bfloat16* __restrict__ VT){
  __shared__ short t[64][65];
  int b = blockIdx.z, s0 = blockIdx.y*64, h0 = blockIdx.x*64;
  int r = threadIdx.x >> 6, c = threadIdx.x & 63;
  const short* vp = (const short*)V + ((size_t)(b*512 + s0))*1024 + h0;
  #pragma unroll
  for (int p=0;p<16;p++) t[p*4+r][c] = vp[(size_t)(p*4+r)*1024 + c];
  __syncthreads();
  short* op = (short*)VT + ((size_t)(b*1024 + h0))*512 + s0;
  #pragma unroll
  for (int p=0;p<16;p++) op[(size_t)(p*4+r)*512 + c] = t[c][p*4+r];
}

// ---------------- GEMM: C = scale*(A @ B^T) + bias ----------------
// EPI 0: C bf16 [M,N]. EPI 2: C f32 at d_out with row permutation + exp-partials to psum.
template<int EPI>
__global__ __launch_bounds__(256) void k_gemm(const __hip_bfloat16* __restrict__ A,
    const __hip_bfloat16* __restrict__ Bm, const float* __restrict__ bias,
    void* __restrict__ Cp, float* __restrict__ psum, int M, int N, int K, float scale){
  __shared__ __hip_bfloat16 sA[128*40];
  __shared__ __hip_bfloat16 sB[128*40];
  __shared__ float sPart[(EPI==2)?128:1][33];
  int tid = threadIdx.x;
  int lane = tid & 63, w = tid >> 6;
  int wr = w >> 1, wc = w & 1;
  int m0 = blockIdx.y*128, n0 = blockIdx.x*128;
  int lrow = lane & 15, lk = lane >> 4;
  f32x4 acc[4][4] = {};
  for (int k0 = 0; k0 < K; k0 += 32){
    __syncthreads();
    #pragma unroll
    for (int l0 = 0; l0 < 1024; l0 += 256){
      int l = l0 + tid;
      int half = l >> 9;
      int ch = l & 511;
      int row = ch >> 2, seg = ch & 3;
      const __hip_bfloat16* src = half ? (Bm + (size_t)(n0+row)*K + k0 + seg*8)
                                       : (A  + (size_t)(m0+row)*K + k0 + seg*8);
      __hip_bfloat16* dst = (half ? sB : sA) + row*40 + seg*8;
      *(short8*)dst = *(const short8*)src;
    }
    __syncthreads();
    short8 af[4], bfq[4];
    #pragma unroll
    for (int mi=0;mi<4;mi++) af[mi]  = *(short8*)(sA + (wr*64+mi*16+lrow)*40 + lk*8);
    #pragma unroll
    for (int ni=0;ni<4;ni++) bfq[ni] = *(short8*)(sB + (wc*64+ni*16+lrow)*40 + lk*8);
    #pragma unroll
    for (int mi=0;mi<4;mi++)
      #pragma unroll
      for (int ni=0;ni<4;ni++)
        acc[mi][ni] = __builtin_amdgcn_mfma_f32_16x16x32_bf16(af[mi], bfq[ni], acc[mi][ni], 0,0,0);
  }
  int crow0 = (lane>>4)*4;
  int ccol = lane & 15;
  float es[4][4];
  #pragma unroll
  for (int mi=0;mi<4;mi++)
    #pragma unroll
    for (int j=0;j<4;j++) es[mi][j] = 0.f;
  #pragma unroll
  for (int mi=0;mi<4;mi++)
    #pragma unroll
    for (int ni=0;ni<4;ni++){
      int gn = n0 + wc*64 + ni*16 + ccol;
      float bv = bias ? bias[gn] : 0.0f;
      #pragma unroll
      for (int j=0;j<4;j++){
        int gm = m0 + wr*64 + mi*16 + crow0 + j;
        float v = acc[mi][ni][j]*scale + bv;
        if (EPI==0){
          ((__hip_bfloat16*)Cp)[(size_t)gm*N + gn] = __float2bfloat16(v);
        } else {
          int tt = gm >> 4, bb = gm & 15;
          ((float*)Cp)[(size_t)(bb*128+tt)*N + gn] = v;
          es[mi][j] += __expf(v);
        }
      }
    }
  if (EPI==2){
    #pragma unroll
    for (int mi=0;mi<4;mi++)
      #pragma unroll
      for (int j=0;j<4;j++)
        sPart[wr*64+mi*16+crow0+j][wc*16+ccol] = es[mi][j];
    __syncthreads();
    int row = tid >> 1, hh = tid & 1;
    float s2 = 0.f;
    #pragma unroll
    for (int k=0;k<16;k++) s2 += sPart[row][hh*16+k];
    s2 += __shfl_xor(s2, 1);
    if (hh == 0){
      int gm = m0 + row;
      psum[(size_t)((gm&15)*128 + (gm>>4))*256 + blockIdx.x] = s2;
    }
  }
}

// ---------------- persistent decoder: sentinel-spin tag-dataflow (R9, proven) ----------------
// 4 groups of 64 blocks; group g owns batches 4g..4g+3.
// Producers store tagged payload words (bf16|ver<<16) in one burst, no flags.
// Consumers spin on ONE sentinel word per producer (64 u32/block/round), then
// single-shot bulk-read the payload with per-word tag verify (retry if straggler).
__global__ __launch_bounds__(256, 1) void k_decode(
    const __hip_bfloat16* __restrict__ KQ, const __hip_bfloat16* __restrict__ VT,
    const float* __restrict__ sb, const __hip_bfloat16* __restrict__ Whh,
    const __hip_bfloat16* __restrict__ Wih2, const float* __restrict__ gconst,
    const float* __restrict__ ec,
    unsigned* __restrict__ hv, unsigned* __restrict__ ev,
    unsigned* __restrict__ cv, __hip_bfloat16* __restrict__ hall,
    float* __restrict__ outH, float* __restrict__ outC)
{
  __shared__ __attribute__((aligned(16))) __hip_bfloat16 h4L[4][1032];
  __shared__ __attribute__((aligned(16))) float eL[528];
  __shared__ __attribute__((aligned(16))) float sPf[1024];
  __shared__ __attribute__((aligned(16))) __hip_bfloat16 sCtx[64];
  __shared__ float sSb[32];
  __shared__ float sGc[64];
  __shared__ float sRed[4];

  const int tid = threadIdx.x;
  const int lane = tid & 63, wv = tid >> 6;
  const int l16 = lane & 15, lhi = lane >> 4;
  const int blk = blockIdx.x;
  const int xcd = blk & 7, slot = blk >> 3;
  const int grp = xcd >> 1, half = xcd & 1;
  const int bloc = half*2 + (slot >> 4);
  const int chunk = slot & 15;
  const int g4 = grp*4;
  const int b = g4 + bloc;
  const int j0 = (half*32 + slot) * 16;

  // gate-weight fragments: waves 0-1 Whh (h part), waves 2-3 Wih2 (ctx part)
  short8 wfrag[64];
  {
    const __hip_bfloat16* wsrc = (wv < 2) ? Whh : Wih2;
    const int koff = (wv & 1) * 512;
    #pragma unroll
    for (int tt = 0; tt < 4; tt++)
      #pragma unroll
      for (int kt = 0; kt < 16; kt++)
        wfrag[tt*16+kt] = *(const short8*)(wsrc + (size_t)(tt*1024 + j0 + l16)*1024 + koff + kt*32 + lhi*8);
  }
  if (tid < 32) sSb[tid] = sb[b*512 + chunk*32 + tid];
  if (tid < 64) sGc[(tid>>4)*16 + (tid&15)] = gconst[(tid>>4)*1024 + j0 + (tid&15)];
  float creg = 0.f;
  if (tid < 64) creg = ec[(size_t)(g4 + (tid>>4))*1024 + j0 + (tid&15)];

  const __hip_bfloat16* kqBlk = KQ + ((size_t)(b*512 + chunk*32))*1024;
  const int ar = (l16 < 4) ? l16 : 3;
  const short8 zfrag = {};
  f32x4 gacc[4] = {};

  // sentinel addresses (per-wave, lane-mapped)
  const unsigned* snH = hv + (size_t)g4*1024 + lane*16;                        // 64 producers (gate blocks)
  const unsigned* snE = ev + (size_t)b*512 + (lane & 15)*32;                   // 16 producers (own-batch chunks)
  const unsigned* snC = cv + (size_t)(g4 + (lane>>4))*1024 + (lane&15)*64;     // 64 producers (attention blocks)

  for (int st = 0; st < 128; ++st){
    const unsigned wantH = (unsigned)st;
    const unsigned wantN = (unsigned)(st+1);

    // ---- A: spin h sentinels, stage OWN batch, scores -> e store ----
    { unsigned v; do { v = ld_u32v(snH); } while (!__all((int)((v>>16) == wantH))); }
    {
      const u64* s0 = (const u64*)(hv + (size_t)b*1024) + tid*2;
      u64 a0, a1; bool ok;
      do {
        a0 = ld_u64v(s0); a1 = ld_u64v(s0+1);
        ok = (((unsigned)a0>>16)==wantH) && ((unsigned)(a0>>48)==wantH)
          && (((unsigned)a1>>16)==wantH) && ((unsigned)(a1>>48)==wantH);
      } while(!ok);
      short4v o = { (short)(unsigned)a0, (short)(a0>>32), (short)(unsigned)a1, (short)(a1>>32) };
      *(short4v*)&h4L[bloc][tid*4] = o;
    }
    __syncthreads();
    {
      int row = tid >> 3, kx = tid & 7;
      const __hip_bfloat16* kp = kqBlk + (size_t)row*1024 + kx*8;
      float acc = 0.f;
      #pragma unroll
      for (int q = 0; q < 16; q++){
        short8 kv = *(const short8*)(kp + q*64);
        short8 hv8 = *(const short8*)&h4L[bloc][kx*8 + q*64];
        #pragma unroll
        for (int e2 = 0; e2 < 8; e2++) acc += bf2f(hv8[e2]) * bf2f(kv[e2]);
      }
      acc += __shfl_xor(acc, 1); acc += __shfl_xor(acc, 2); acc += __shfl_xor(acc, 4);
      if (kx == 0)
        st_u32v(&ev[(size_t)b*512 + chunk*32 + row], bfbits(expf(acc + sSb[row])) | (wantN<<16));
    }
    // stage other 3 batches (sentinels already confirmed; verified bulk reads)
    #pragma unroll
    for (int rr = 1; rr < 4; rr++){
      int r = (bloc + rr) & 3;
      const u64* s0 = (const u64*)(hv + (size_t)(g4 + r)*1024) + tid*2;
      u64 a0, a1; bool ok;
      do {
        a0 = ld_u64v(s0); a1 = ld_u64v(s0+1);
        ok = (((unsigned)a0>>16)==wantH) && ((unsigned)(a0>>48)==wantH)
          && (((unsigned)a1>>16)==wantH) && ((unsigned)(a1>>48)==wantH);
      } while(!ok);
      short4v o = { (short)(unsigned)a0, (short)(a0>>32), (short)(unsigned)a1, (short)(a1>>32) };
      *(short4v*)&h4L[r][tid*4] = o;
    }
    __syncthreads();
    // h-part gate MFMA (waves 0-1) — overlaps e flight
    if (wv < 2){
      const int ko = (wv & 1) * 512;
      #pragma unroll
      for (int kt = 0; kt < 16; kt++){
        short8 a = *(const short8*)&h4L[ar][ko + kt*32 + lhi*8];
        a = (l16 < 4) ? a : zfrag;
        #pragma unroll
        for (int tt = 0; tt < 4; tt++)
          gacc[tt] = __builtin_amdgcn_mfma_f32_16x16x32_bf16(a, wfrag[tt*16+kt], gacc[tt], 0,0,0);
      }
    }

    // ---- B: spin e sentinels, bulk e read, L reduce, ctx slice, ctx store ----
    { unsigned v; do { v = ld_u32v(snE); } while (!__all((int)((v>>16) == wantN))); }
    {
      const u64* s = (const u64*)(ev + (size_t)b*512) + tid;
      u64 v;
      do { v = ld_u64v(s); }
      while(!((((unsigned)v>>16)==wantN) && ((unsigned)(v>>48)==wantN)));
      float e0 = bf2f((short)(unsigned)v), e1 = bf2f((short)(v>>32));
      int i0 = tid*2, pad = (tid>>6)<<2;
      eL[i0 + pad] = e0; eL[i0+1 + pad] = e1;
      float lp = e0 + e1;
      for (int off=32; off; off>>=1) lp += __shfl_xor(lp, off);
      if (lane == 0) sRed[wv] = lp;
    }
    __syncthreads();
    {
      float Linv = 1.0f/(sRed[0]+sRed[1]+sRed[2]+sRed[3]);
      int hloc = tid >> 2, sc = (tid & 3)*128;
      const __hip_bfloat16* vp = VT + ((size_t)(b*1024 + chunk*64 + hloc))*512 + sc;
      const float* epp = eL + sc + ((sc>>7)<<2);
      float a = 0.f;
      #pragma unroll
      for (int q = 0; q < 16; q++){
        short8 vv = *(const short8*)(vp + q*8);
        float4 e0 = *(const float4*)(epp + q*8);
        float4 e1 = *(const float4*)(epp + q*8 + 4);
        a += e0.x*bf2f(vv[0]) + e0.y*bf2f(vv[1]) + e0.z*bf2f(vv[2]) + e0.w*bf2f(vv[3]);
        a += e1.x*bf2f(vv[4]) + e1.y*bf2f(vv[5]) + e1.z*bf2f(vv[6]) + e1.w*bf2f(vv[7]);
      }
      a += __shfl_xor(a, 1); a += __shfl_xor(a, 2);
      if ((tid & 3) == 0) sCtx[hloc] = __float2bfloat16(a * Linv);
    }
    __syncthreads();
    if (tid < 64){
      unsigned short cbts; __builtin_memcpy(&cbts, &sCtx[tid], 2);
      st_u32v(&cv[(size_t)b*1024 + chunk*64 + tid], (unsigned)cbts | (wantN<<16));
    }

    // ---- C: spin ctx sentinels, bulk stage ctx, ctx-MFMA (waves 2-3), gates, LSTM, h store ----
    { unsigned v; do { v = ld_u32v(snC); } while (!__all((int)((v>>16) == wantN))); }
    {
      int r = tid >> 6, c0 = (tid & 63)*16;
      const u64* s = (const u64*)(cv + (size_t)(g4 + r)*1024 + c0);
      u64 v[8]; bool ok;
      do {
        ok = true;
        #pragma unroll
        for (int i=0;i<8;i++) v[i] = ld_u64v(s+i);
        #pragma unroll
        for (int i=0;i<8;i++) ok &= (((unsigned)v[i]>>16)==wantN) && ((unsigned)(v[i]>>48)==wantN);
      } while(!ok);
      #pragma unroll
      for (int i=0;i<8;i++){
        short2 o = { (short)(unsigned)v[i], (short)(v[i]>>32) };
        *(short2*)&h4L[r][c0 + 2*i] = *(short2*)&o;
      }
    }
    __syncthreads();
    if (wv >= 2){
      const int ko = (wv & 1) * 512;
      #pragma unroll
      for (int kt = 0; kt < 16; kt++){
        short8 a = *(const short8*)&h4L[ar][ko + kt*32 + lhi*8];
        a = (l16 < 4) ? a : zfrag;
        #pragma unroll
        for (int tt = 0; tt < 4; tt++)
          gacc[tt] = __builtin_amdgcn_mfma_f32_16x16x32_bf16(a, wfrag[tt*16+kt], gacc[tt], 0,0,0);
      }
    }
    if (lhi == 0){
      #pragma unroll
      for (int tt = 0; tt < 4; tt++)
        *(f32x4*)&sPf[(wv*64 + tt*16 + l16)*4] = gacc[tt];
    }
    #pragma unroll
    for (int tt = 0; tt < 4; tt++) gacc[tt] = (f32x4){0.f,0.f,0.f,0.f};
    __syncthreads();
    if (tid < 64){
      int bb = tid >> 4, jj = tid & 15;
      float gv[4];
      #pragma unroll
      for (int tt = 0; tt < 4; tt++){
        float s = sGc[tt*16 + jj];
        #pragma unroll
        for (int w2 = 0; w2 < 4; w2++) s += sPf[(w2*64 + tt*16 + jj)*4 + bb];
        gv[tt] = s;
      }
      float si = 1.f/(1.f+expf(-gv[0]));
      float sf = 1.f/(1.f+expf(-gv[1]));
      float so = 1.f/(1.f+expf(-gv[3]));
      float c2 = sf*creg + si*tanhf(gv[2]);
      float h2 = so*tanhf(c2);
      creg = c2;
      int gb = g4 + bb;
      unsigned hb = bfbits(h2);
      st_u32v(&hv[(size_t)gb*1024 + j0 + jj], hb | (wantN<<16));
      __hip_bfloat16 hbv; unsigned short hu = (unsigned short)hb; __builtin_memcpy(&hbv, &hu, 2);
      hall[((size_t)(st*16 + gb))*1024 + j0 + jj] = hbv;
      if (st == 127){ outH[gb*1024 + j0 + jj] = h2; outC[gb*1024 + j0 + jj] = c2; }
    }
  }
}

// ---------------- apply log-softmax using fused exp-partials ----------------
__global__ __launch_bounds__(256) void k_apply(float* __restrict__ out, const float* __restrict__ psum){
  int r = blockIdx.x;
  int tid = threadIdx.x;
  __shared__ float red[4];
  float s = (tid < 250) ? psum[(size_t)r*256 + tid] : 0.f;
  for (int off=32; off; off>>=1) s += __shfl_xor(s, off);
  if ((tid&63)==0) red[tid>>6] = s;
  __syncthreads();
  float L = logf(red[0]+red[1]+red[2]+red[3]);
  float* p = out + (size_t)r*32000;
  for (int i = tid*4; i < 32000; i += 1024){
    float4 v = *(float4*)(p+i);
    v.x-=L; v.y-=L; v.z-=L; v.w-=L;
    *(float4*)(p+i) = v;
  }
}

extern "C" void kernel_launch(void* const* d_in, const int* in_sizes, int n_in,
                              void* d_out, int out_size, void* d_ws, size_t ws_size,
                              hipStream_t stream){
  const float* enc = (const float*)d_in[0];
  const float* eh  = (const float*)d_in[1];
  const float* ec  = (const float*)d_in[2];
  const float* emb = (const float*)d_in[3];
  const float* Wq  = (const float*)d_in[4];
  const float* bq  = (const float*)d_in[5];
  const float* Wk  = (const float*)d_in[6];
  const float* bk  = (const float*)d_in[7];
  const float* Wv  = (const float*)d_in[8];
  const float* bv  = (const float*)d_in[9];
  const float* Wih = (const float*)d_in[10];
  const float* bih = (const float*)d_in[11];
  const float* Whh = (const float*)d_in[12];
  const float* bhh = (const float*)d_in[13];
  const float* Wo  = (const float*)d_in[14];
  const float* bo  = (const float*)d_in[15];

  char* ws = (char*)d_ws;
  __hip_bfloat16* encbf = (__hip_bfloat16*)(ws + o_encbf);
  __hip_bfloat16* kbf   = (__hip_bfloat16*)(ws + o_kbf);
  __hip_bfloat16* wkbf  = (__hip_bfloat16*)(ws + o_wkbf);
  __hip_bfloat16* wvbf  = (__hip_bfloat16*)(ws + o_wvbf);
  __hip_bfloat16* wqtbf = (__hip_bfloat16*)(ws + o_wqtbf);
  __hip_bfloat16* vt    = (__hip_bfloat16*)(ws + o_vt);
  __hip_bfloat16* woutbf= (__hip_bfloat16*)(ws + o_wout);
  __hip_bfloat16* kq    = (__hip_bfloat16*)(ws + o_kq);
  __hip_bfloat16* vbf   = (__hip_bfloat16*)(ws + o_vbf);
  __hip_bfloat16* wih2  = (__hip_bfloat16*)(ws + o_wih2);
  __hip_bfloat16* whhbf = (__hip_bfloat16*)(ws + o_whh);
  __hip_bfloat16* hall  = (__hip_bfloat16*)(ws + o_hall);
  float* gconst = (float*)(ws + o_gconst);
  float* sbp    = (float*)(ws + o_sb);
  unsigned* hvp = (unsigned*)(ws + o_hv);
  unsigned* evp = (unsigned*)(ws + o_ev);
  unsigned* cvp = (unsigned*)(ws + o_cv);
  float* psum   = (float*)(ws + o_psum);
  float* outP   = (float*)d_out;
  float* outH   = outP + 65536000;
  float* outC   = outH + 16384;

  // ---- precompute ----
  k_convert<<<1024,256,0,stream>>>(enc, encbf, 8388608);
  k_convert<<<256,256,0,stream>>>(Wk, wkbf, 1048576);
  k_convert<<<256,256,0,stream>>>(Wv, wvbf, 1048576);
  k_tcvt<<<dim3(16,16),256,0,stream>>>(Wq, wqtbf);
  k_gemm<0><<<dim3(8,64),256,0,stream>>>(encbf, wkbf, bk, kbf, nullptr, 8192,1024,1024, 1.f);
  k_gemm<0><<<dim3(8,64),256,0,stream>>>(encbf, wvbf, bv, vbf, nullptr, 8192,1024,1024, 1.f);
  k_gemm<0><<<dim3(8,64),256,0,stream>>>(kbf, wqtbf, (const float*)nullptr, kq, nullptr, 8192,1024,1024, 0.03125f);
  k_vtrans<<<dim3(16,8,16),256,0,stream>>>(vbf, vt);
  k_sb<<<2048,256,0,stream>>>(kbf, bq, sbp);
  k_extract<<<1024,256,0,stream>>>(Wih, wih2);
  k_convert<<<1024,256,0,stream>>>(Whh, whhbf, 4194304);
  k_gconst<<<1024,256,0,stream>>>(emb, Wih, bih, bhh, gconst);
  k_init<<<160,256,0,stream>>>(eh, hvp);

  // ---- recurrence: persistent sentinel-dataflow kernel (R9, proven) ----
  {
    const __hip_bfloat16* a_kq = kq; const __hip_bfloat16* a_vt = vt;
    const float* a_sb = sbp; const __hip_bfloat16* a_whh = whhbf;
    const __hip_bfloat16* a_wih = wih2; const float* a_gc = gconst;
    const float* a_ec = ec;
    unsigned* a_h = hvp; unsigned* a_e = evp; unsigned* a_c = cvp;
    __hip_bfloat16* a_ha = hall;
    float* a_oh = outH; float* a_oc = outC;
    void* args[] = { &a_kq, &a_vt, &a_sb, &a_whh, &a_wih, &a_gc, &a_ec,
                     &a_h, &a_e, &a_c, &a_ha, &a_oh, &a_oc };
    hipError_t err = hipLaunchCooperativeKernel((void*)k_decode, dim3(256), dim3(256),
                                                args, 0u, stream);
    if (err != hipSuccess){
      k_decode<<<256,256,0,stream>>>(kq, vt, sbp, whhbf, wih2, gconst, ec,
                                     hvp, evp, cvp, hall, outH, outC);
    }
  }

  // ---- logits + fused log-softmax ----
  k_convert<<<2048,256,0,stream>>>(Wo, woutbf, 32768000);
  k_gemm<2><<<dim3(250,16),256,0,stream>>>(hall, woutbf, bo, d_out, psum, 2048,32000,1024, 1.f);
  k_apply<<<2048,256,0,stream>>>(outP, psum);
}